// Round 2
// baseline (6862.743 us; speedup 1.0000x reference)
//
#include <hip/hip_runtime.h>
#include <hip/hip_bf16.h>
#include <stddef.h>
#include <stdint.h>

#define T_STEPS 512
#define B_SZ 256
#define H_SZ 256
#define G4H 1024  // 4*H
#define SPIN_MAX (1 << 18)

typedef __attribute__((ext_vector_type(8))) short bf16x8;
typedef __attribute__((ext_vector_type(4))) float f32x4;

__device__ __forceinline__ unsigned short f2bf(float f) {
  union { float f; unsigned u; } v; v.f = f;
  unsigned r = v.u + 0x7fffu + ((v.u >> 16) & 1u);
  return (unsigned short)(r >> 16);
}
__device__ __forceinline__ float bf2f(unsigned short h) {
  union { unsigned u; float f; } v; v.u = ((unsigned)h) << 16; return v.f;
}
__device__ __forceinline__ float sigmoid_f(float x) {
  return 1.0f / (1.0f + __expf(-x));
}
__device__ __forceinline__ float tanh_f(float x) {
  return 1.0f - 2.0f / (__expf(2.0f * x) + 1.0f);
}

// ---------------- prep: fp32->bf16 weights, bias sum, state init, flag zeroing ----------
__global__ void prep_kernel(const float* __restrict__ h0, const float* __restrict__ c0,
                            const float* __restrict__ W_ih, const float* __restrict__ W_hh,
                            const float* __restrict__ b_ih, const float* __restrict__ b_hh,
                            unsigned short* __restrict__ Wih_bf, unsigned short* __restrict__ Whh_bf,
                            float* __restrict__ bias, unsigned short* __restrict__ h_st,
                            float* __restrict__ c_st, int* __restrict__ flags) {
  int i = blockIdx.x * 256 + threadIdx.x;
  int stride = gridDim.x * 256;
  for (int k = i; k < G4H * H_SZ; k += stride) {
    Wih_bf[k] = f2bf(W_ih[k]);
    Whh_bf[k] = f2bf(W_hh[k]);
  }
  for (int k = i; k < B_SZ * H_SZ; k += stride) {
    h_st[k] = f2bf(h0[k]);   // parity 0
    c_st[k] = c0[k];
  }
  for (int k = i; k < G4H; k += stride) bias[k] = b_ih[k] + b_hh[k];
  for (int k = i; k < T_STEPS * 64; k += stride) flags[k] = 0;
}

// ---------------- K1: xg = bf16( embed[idx] @ W_ih^T + b_ih + b_hh ), swizzled layout.
// Swizzle: value (t_local, b, n) with n=g*256+j ->
//   flat = ((((t*16 + bg)*4 + jb)*4 + w)*64 + (quad*16 + (j&15)))*16 + g*4 + r
//   where bg=b>>4, m=b&15, quad=m>>2, r=m&3, jb=j>>6, w=(j>>4)&3.
__global__ __launch_bounds__(256, 2) void xgate_kernel(
    const int* __restrict__ enc, const float* __restrict__ embed,
    const unsigned short* __restrict__ Wih_bf, const float* __restrict__ bias,
    unsigned short* __restrict__ xg, int t0, int Ci) {
  __shared__ unsigned short As[64][264];
  const int tid = threadIdx.x;
  const int mbase = blockIdx.x * 64;

  // stage A tile: 64 rows of embed (gather), fp32 -> bf16
  {
    int r = tid >> 2, q = tid & 3;
    int mg = mbase + r;
    int s = mg >> 8, b = mg & 255;
    int vid = enc[(t0 + s) * B_SZ + b];
    const float4* src = (const float4*)(embed + (size_t)vid * H_SZ) + q * 16;
#pragma unroll
    for (int j = 0; j < 16; ++j) {
      float4 x = src[j];
      ushort4 o;
      o.x = f2bf(x.x); o.y = f2bf(x.y); o.z = f2bf(x.z); o.w = f2bf(x.w);
      *(ushort4*)&As[r][q * 64 + j * 4] = o;
    }
  }
  __syncthreads();

  const int wave = tid >> 6, lane = tid & 63;
  const int lrow = lane & 15, quad = lane >> 4;
  const int g = blockIdx.y;  // gate index: n = g*256 + (wave*64 + nt*16 + lrow)

  // A fragments fully resident: 4 m-tiles x 8 k-steps
  bf16x8 af[4][8];
#pragma unroll
  for (int mt = 0; mt < 4; ++mt)
#pragma unroll
    for (int ks = 0; ks < 8; ++ks)
      af[mt][ks] = *(const bf16x8*)&As[mt * 16 + lrow][ks * 32 + quad * 8];

#pragma unroll
  for (int nt = 0; nt < 4; ++nt) {
    const int nrow = g * 256 + wave * 64 + nt * 16 + lrow;  // W_ih row
    const unsigned short* wrow = Wih_bf + (size_t)nrow * H_SZ + quad * 8;
    bf16x8 bf[8];
#pragma unroll
    for (int ks = 0; ks < 8; ++ks) bf[ks] = *(const bf16x8*)(wrow + ks * 32);
    const float bs = bias[nrow];
#pragma unroll
    for (int mt = 0; mt < 4; ++mt) {
      f32x4 a = {0.f, 0.f, 0.f, 0.f};
#pragma unroll
      for (int ks = 0; ks < 8; ++ks)
        a = __builtin_amdgcn_mfma_f32_16x16x32_bf16(af[mt][ks], bf[ks], a, 0, 0, 0);
      // m = mbase + mt*16 + quad*4 + r (r=0..3 contiguous in swizzled layout)
      const int mrow = mbase + mt * 16;         // multiple of 16
      const int s_loc = mrow >> 8;
      const int bg = (mrow >> 4) & 15;
      const size_t off =
          ((((size_t)s_loc * 16 + bg) * 4 + wave) * 4 + nt) * 1024 +
          (size_t)(quad * 16 + lrow) * 16 + g * 4;
      ushort4 o;
      o.x = f2bf(a[0] + bs); o.y = f2bf(a[1] + bs);
      o.z = f2bf(a[2] + bs); o.w = f2bf(a[3] + bs);
      *(ushort4*)(xg + off) = o;
    }
  }
}

// ---------------- K2: recurrent. 64 blocks: bg = blk>>2 (16 batches), jb = blk&3 (64 j's).
// W_hh slice register-resident; per-step h exchange through L3 with flag sync.
__global__ __launch_bounds__(256, 1) void lstm_kernel(
    const unsigned short* __restrict__ Whh_bf, const unsigned short* __restrict__ xg,
    unsigned short* __restrict__ h_st, float* __restrict__ c_st,
    int* __restrict__ flags, float* __restrict__ out, int t0, int Ci) {
  const int tid = threadIdx.x, wave = tid >> 6, lane = tid & 63;
  const int lrow = lane & 15, quad = lane >> 4;
  const int bg = blockIdx.x >> 2, jb = blockIdx.x & 3;
  const int b0 = bg * 16;
  const int jcol = jb * 64 + wave * 16 + lrow;  // this lane's hidden column

  // W_hh fragments: rows n = g*256 + jcol, cols k = ks*32 + quad*8 .. +8  (128 VGPRs)
  bf16x8 wf[4][8];
#pragma unroll
  for (int g = 0; g < 4; ++g)
#pragma unroll
    for (int ks = 0; ks < 8; ++ks)
      wf[g][ks] = *(const bf16x8*)(Whh_bf + (size_t)(g * 256 + jcol) * H_SZ + ks * 32 + quad * 8);

  float creg[4], hv[4];
#pragma unroll
  for (int r = 0; r < 4; ++r)
    creg[r] = c_st[(size_t)(b0 + quad * 4 + r) * H_SZ + jcol];

#pragma unroll 1
  for (int s = 0; s < Ci; ++s) {
    const int i = t0 + s;          // absolute timestep: consumes h_i, produces h_{i+1}
    const int rp = i & 1;          // parity holding h_i
    const int wp = rp ^ 1;

    // xg prefetch (independent of h) — 32 contiguous bytes per lane
    const size_t xoff = ((((size_t)s * 16 + bg) * 4 + jb) * 4 + wave) * 1024 + (size_t)lane * 16;
    uint4 x0 = *(const uint4*)(xg + xoff);
    uint4 x1 = *(const uint4*)(xg + xoff + 8);

    if (s > 0) {
      // wait for all 4 peers to have produced h_i (flag[i-1])
      if (tid < 4) {
        const int* fp = flags + (size_t)(i - 1) * 64 + bg * 4 + tid;
        int spins = 0;
        while (__hip_atomic_load(fp, __ATOMIC_RELAXED, __HIP_MEMORY_SCOPE_AGENT) == 0 &&
               spins < SPIN_MAX)
          ++spins;
      }
      __syncthreads();
      __threadfence();  // acquire: invalidate stale L1/L2 before reading peer h
    }

    // A-fragments: h_i rows from global (L3 after fences)
    const unsigned short* hrow = h_st + ((size_t)rp * B_SZ + b0 + lrow) * H_SZ + quad * 8;
    bf16x8 af[8];
#pragma unroll
    for (int ks = 0; ks < 8; ++ks) af[ks] = *(const bf16x8*)(hrow + ks * 32);

    f32x4 acc[4];
#pragma unroll
    for (int g = 0; g < 4; ++g) acc[g] = (f32x4){0.f, 0.f, 0.f, 0.f};
#pragma unroll
    for (int ks = 0; ks < 8; ++ks)
#pragma unroll
      for (int g = 0; g < 4; ++g)
        acc[g] = __builtin_amdgcn_mfma_f32_16x16x32_bf16(af[ks], wf[g][ks], acc[g], 0, 0, 0);

    // elementwise: lane owns (m = quad*4+r, j = jcol), r = 0..3
    const unsigned short* xv0 = (const unsigned short*)&x0;  // g=0,1
    const unsigned short* xv1 = (const unsigned short*)&x1;  // g=2,3
#pragma unroll
    for (int r = 0; r < 4; ++r) {
      float gi = acc[0][r] + bf2f(xv0[r]);
      float gf = acc[1][r] + bf2f(xv0[4 + r]);
      float gg = acc[2][r] + bf2f(xv1[r]);
      float go = acc[3][r] + bf2f(xv1[4 + r]);
      gi = sigmoid_f(gi);
      gf = sigmoid_f(gf);
      gg = tanh_f(gg);
      go = sigmoid_f(go);
      float c = gf * creg[r] + gi * gg;
      creg[r] = c;
      float h = go * tanh_f(c);
      hv[r] = h;
      h_st[((size_t)wp * B_SZ + b0 + quad * 4 + r) * H_SZ + jcol] = f2bf(h);
    }

    __threadfence();  // release: drain + write back h stores to coherence point
    __syncthreads();
    if (tid == 0)
      __hip_atomic_store(flags + (size_t)i * 64 + bg * 4 + jb, 1,
                         __ATOMIC_RELAXED, __HIP_MEMORY_SCOPE_AGENT);

    if (i == T_STEPS - 1) {
#pragma unroll
      for (int r = 0; r < 4; ++r) {
        const size_t gidx = (size_t)(b0 + quad * 4 + r) * H_SZ + jcol;
        out[gidx] = hv[r];
        out[(size_t)B_SZ * H_SZ + gidx] = creg[r];
      }
    }
  }

  // persist c across chunk launches (h already in h_st at parity (t0+Ci)&1)
#pragma unroll
  for (int r = 0; r < 4; ++r)
    c_st[(size_t)(b0 + quad * 4 + r) * H_SZ + jcol] = creg[r];
}

extern "C" void kernel_launch(void* const* d_in, const int* in_sizes, int n_in,
                              void* d_out, int out_size, void* d_ws, size_t ws_size,
                              hipStream_t stream) {
  const int* enc = (const int*)d_in[0];
  const float* h0 = (const float*)d_in[1];
  const float* c0 = (const float*)d_in[2];
  const float* embed = (const float*)d_in[3];
  const float* W_ih = (const float*)d_in[4];
  const float* W_hh = (const float*)d_in[5];
  const float* b_ih = (const float*)d_in[6];
  const float* b_hh = (const float*)d_in[7];
  float* out = (float*)d_out;

  char* ws = (char*)d_ws;
  unsigned short* Wih_bf = (unsigned short*)(ws);                  // 512 KB
  unsigned short* Whh_bf = (unsigned short*)(ws + (512 << 10));    // 512 KB
  float* bias = (float*)(ws + (1024 << 10));                       // 4 KB
  unsigned short* h_st = (unsigned short*)(ws + (1028 << 10));     // 2 x 128 KB (double-buffered)
  float* c_st = (float*)(ws + (1284 << 10));                       // 256 KB
  int* flags = (int*)(ws + (1540 << 10));                          // 128 KB (512 x 16 x 4)
  const size_t fixed = (size_t)(1668) << 10;
  unsigned short* xg = (unsigned short*)(ws + fixed);

  const size_t per_step = (size_t)B_SZ * G4H * 2;  // 512 KB per timestep (bf16)
  int C = 1;
  if (ws_size > fixed + per_step) {
    size_t c = (ws_size - fixed) / per_step;
    C = (c > T_STEPS) ? T_STEPS : (int)c;
  }

  prep_kernel<<<dim3(256), dim3(256), 0, stream>>>(h0, c0, W_ih, W_hh, b_ih, b_hh,
                                                   Wih_bf, Whh_bf, bias, h_st, c_st, flags);
  for (int t0 = 0; t0 < T_STEPS; t0 += C) {
    int Ci = (T_STEPS - t0 < C) ? (T_STEPS - t0) : C;
    xgate_kernel<<<dim3(Ci * 4, 4), dim3(256), 0, stream>>>(enc, embed, Wih_bf, bias,
                                                            xg, t0, Ci);
    lstm_kernel<<<dim3(64), dim3(256), 0, stream>>>(Whh_bf, xg, h_st, c_st, flags,
                                                    out, t0, Ci);
  }
}

// Round 4
// 2895.213 us; speedup vs baseline: 2.3704x; 2.3704x over previous
//
#include <hip/hip_runtime.h>
#include <hip/hip_bf16.h>
#include <stddef.h>
#include <stdint.h>

#define T_STEPS 512
#define B_SZ 256
#define H_SZ 256
#define G4H 1024  // 4*H
#define PH 264            // Hs row pitch in shorts (+8 pad: conflict-free af reads)
#define HS_PAR (16 * PH)  // shorts per h parity buffer

typedef __attribute__((ext_vector_type(8))) short bf16x8;
typedef __attribute__((ext_vector_type(4))) float f32x4;

__device__ __forceinline__ unsigned short f2bf(float f) {
  union { float f; unsigned u; } v; v.f = f;
  unsigned r = v.u + 0x7fffu + ((v.u >> 16) & 1u);
  return (unsigned short)(r >> 16);
}
__device__ __forceinline__ float bf2f(unsigned short h) {
  union { unsigned u; float f; } v; v.u = ((unsigned)h) << 16; return v.f;
}
__device__ __forceinline__ float sigmoid_f(float x) {
  return 1.0f / (1.0f + __expf(-x));
}
__device__ __forceinline__ float tanh_f(float x) {
  return 1.0f - 2.0f / (__expf(2.0f * x) + 1.0f);
}

// ---------------- prep: fp32->bf16 weights, bias sum, state init ----------------
__global__ void prep_kernel(const float* __restrict__ h0, const float* __restrict__ c0,
                            const float* __restrict__ W_ih, const float* __restrict__ W_hh,
                            const float* __restrict__ b_ih, const float* __restrict__ b_hh,
                            unsigned short* __restrict__ Wih_bf, unsigned short* __restrict__ Whh_bf,
                            float* __restrict__ bias, unsigned short* __restrict__ h_st,
                            float* __restrict__ c_st) {
  int i = blockIdx.x * 256 + threadIdx.x;
  int stride = gridDim.x * 256;
  for (int k = i; k < G4H * H_SZ; k += stride) {
    Wih_bf[k] = f2bf(W_ih[k]);
    Whh_bf[k] = f2bf(W_hh[k]);
  }
  for (int k = i; k < B_SZ * H_SZ; k += stride) {
    h_st[k] = f2bf(h0[k]);
    c_st[k] = c0[k];
  }
  for (int k = i; k < G4H; k += stride) bias[k] = b_ih[k] + b_hh[k];
}

// ---------------- K1: xg = bf16( embed[idx] @ W_ih^T + b_ih + b_hh )
// Swizzled for K2: value (t_loc, b, n), n = g*256 + j ->
//   flat = (((t_loc*16 + bg)*1024) + tid2)*16 + g*4 + r
//   where bg=b>>4, m=b&15, quad=m>>2, r=m&3, tid2 = (j>>4)*64 + quad*16 + (j&15).
__global__ __launch_bounds__(256, 2) void xgate_kernel(
    const int* __restrict__ enc, const float* __restrict__ embed,
    const unsigned short* __restrict__ Wih_bf, const float* __restrict__ bias,
    unsigned short* __restrict__ xg, int t0, int Ci) {
  __shared__ __align__(16) unsigned short As[64][264];
  const int tid = threadIdx.x;
  const int mbase = blockIdx.x * 64;

  // stage A tile: 64 rows of embed (gather), fp32 -> bf16
  {
    int r = tid >> 2, q = tid & 3;
    int mg = mbase + r;
    int s = mg >> 8, b = mg & 255;
    int vid = enc[(t0 + s) * B_SZ + b];
    const float4* src = (const float4*)(embed + (size_t)vid * H_SZ) + q * 16;
#pragma unroll
    for (int j = 0; j < 16; ++j) {
      float4 x = src[j];
      ushort4 o;
      o.x = f2bf(x.x); o.y = f2bf(x.y); o.z = f2bf(x.z); o.w = f2bf(x.w);
      *(ushort4*)&As[r][q * 64 + j * 4] = o;
    }
  }
  __syncthreads();

  const int wave = tid >> 6, lane = tid & 63;
  const int lrow = lane & 15, quad = lane >> 4;
  const int g = blockIdx.y;  // gate index

  // A fragments fully resident: 4 m-tiles x 8 k-steps
  bf16x8 af[4][8];
#pragma unroll
  for (int mt = 0; mt < 4; ++mt)
#pragma unroll
    for (int ks = 0; ks < 8; ++ks)
      af[mt][ks] = *(const bf16x8*)&As[mt * 16 + lrow][ks * 32 + quad * 8];

  const int t_loc = mbase >> 8;

#pragma unroll
  for (int nt = 0; nt < 4; ++nt) {
    const int j = wave * 64 + nt * 16 + lrow;      // hidden column
    const int nrow = g * 256 + j;                  // W_ih row
    const unsigned short* wrow = Wih_bf + (size_t)nrow * H_SZ + quad * 8;
    bf16x8 bf[8];
#pragma unroll
    for (int ks = 0; ks < 8; ++ks) bf[ks] = *(const bf16x8*)(wrow + ks * 32);
    const float bs = bias[nrow];
#pragma unroll
    for (int mt = 0; mt < 4; ++mt) {
      f32x4 a = {0.f, 0.f, 0.f, 0.f};
#pragma unroll
      for (int ks = 0; ks < 8; ++ks)
        a = __builtin_amdgcn_mfma_f32_16x16x32_bf16(af[mt][ks], bf[ks], a, 0, 0, 0);
      // rows m = mbase + mt*16 + quad*4 + r -> bg = (mbase>>4 & 15) + mt, same quad/r
      const int bg = ((mbase >> 4) & 15) + mt;
      const int tid2 = (wave * 4 + nt) * 64 + quad * 16 + lrow;
      const size_t off = (((size_t)t_loc * 16 + bg) * 1024 + tid2) * 16 + g * 4;
      ushort4 o;
      o.x = f2bf(a[0] + bs); o.y = f2bf(a[1] + bs);
      o.z = f2bf(a[2] + bs); o.w = f2bf(a[3] + bs);
      *(ushort4*)(xg + off) = o;
    }
  }
}

// ---------------- K2: recurrent. 16 blocks x 1024 threads (16 waves, 4/SIMD).
// Block owns 16 batches; wave w owns hidden cols j = w*16..w*16+15, ALL 4 gates.
// W split per wave: gates i,f in regs (64 VGPR), gate g in LDS (128 KB),
// gate o streamed from L2 each step (same addrs -> L2-resident).
// h double-buffered in LDS; ONE __syncthreads per step; no cross-block traffic.
// NOTE: parity select is explicit (s&1) — XOR flip is WRONG here because the
// parity stride (8448 B) is not a power of two.
__global__ __launch_bounds__(1024) void lstm_kernel(
    const unsigned short* __restrict__ Whh_bf, const unsigned short* __restrict__ xg,
    unsigned short* __restrict__ h_st, float* __restrict__ c_st,
    float* __restrict__ out, int t0, int Ci) {
  __shared__ __align__(16) unsigned short Hs[2 * HS_PAR];   // 16.5 KB (double-buffered h)
  __shared__ __align__(16) unsigned short Wg[16 * 4096];    // 128 KB (gate-2 fragments)
  // total static LDS ~144.5 KB (gfx950: 160 KB/CU)

  const int tid = threadIdx.x, w = tid >> 6, lane = tid & 63;
  const int lrow = lane & 15, quad = lane >> 4;
  const int b0 = blockIdx.x * 16;
  const int jcol = w * 16 + lrow;

  // gates 0,1 (i,f) resident in registers
  bf16x8 wf0[8], wf1[8];
  {
    const unsigned short* wr0 = Whh_bf + (size_t)(0 * 256 + jcol) * H_SZ + quad * 8;
    const unsigned short* wr1 = Whh_bf + (size_t)(1 * 256 + jcol) * H_SZ + quad * 8;
#pragma unroll
    for (int ks = 0; ks < 8; ++ks) {
      wf0[ks] = *(const bf16x8*)(wr0 + ks * 32);
      wf1[ks] = *(const bf16x8*)(wr1 + ks * 32);
    }
  }
  // gate 2 (g) staged into LDS, fragment-order
  {
    const unsigned short* wr2 = Whh_bf + (size_t)(2 * 256 + jcol) * H_SZ + quad * 8;
#pragma unroll
    for (int ks = 0; ks < 8; ++ks) {
      bf16x8 v = *(const bf16x8*)(wr2 + ks * 32);
      *(bf16x8*)&Wg[w * 4096 + ks * 512 + lane * 8] = v;
    }
  }
  // gate 3 (o): streamed from global (L2) every step
  const unsigned short* wr3 = Whh_bf + (size_t)(3 * 256 + jcol) * H_SZ + quad * 8;

  // stage h into parity-0 LDS buffer
  if (tid < 256) {
    int row = tid >> 4, c16 = (tid & 15) * 16;
    const unsigned short* src = h_st + (size_t)(b0 + row) * H_SZ + c16;
    *(uint4*)&Hs[row * PH + c16] = *(const uint4*)src;
    *(uint4*)&Hs[row * PH + c16 + 8] = *(const uint4*)(src + 8);
  }

  float creg[4], hv[4];
#pragma unroll
  for (int r = 0; r < 4; ++r)
    creg[r] = c_st[(size_t)(b0 + quad * 4 + r) * H_SZ + jcol];

  // xg: 32 contiguous bytes per lane per step, prefetched one step ahead
  const unsigned short* pxg = xg + ((size_t)blockIdx.x * 1024 + tid) * 16;
  uint4 xa0 = *(const uint4*)pxg;
  uint4 xa1 = *(const uint4*)(pxg + 8);
  __syncthreads();

  // parity-0 / parity-1 offsets (bytes), selected per step by s&1
  const int af_base = lrow * (PH * 2) + quad * 16;
  const int hw_base = (quad * 4) * (PH * 2) + jcol * 2;
  const int PAR_B = HS_PAR * 2;  // 8448 bytes
  const unsigned short* wlds = &Wg[w * 4096 + lane * 8];

#pragma unroll 1
  for (int s = 0; s < Ci; ++s) {
    const int rp = (s & 1) * PAR_B;         // read parity
    const int wp = PAR_B - rp;              // write parity (opposite)
    const char* hsr = (const char*)Hs + af_base + rp;
    char* hsw = (char*)Hs + hw_base + wp;

    f32x4 a0 = {0.f, 0.f, 0.f, 0.f}, a1 = a0, a2 = a0, a3 = a0;
#pragma unroll
    for (int ks = 0; ks < 8; ++ks) {
      bf16x8 af = *(const bf16x8*)(hsr + ks * 64);
      bf16x8 w3 = *(const bf16x8*)(wr3 + ks * 32);
      bf16x8 w2 = *(const bf16x8*)(wlds + ks * 512);
      a0 = __builtin_amdgcn_mfma_f32_16x16x32_bf16(af, wf0[ks], a0, 0, 0, 0);
      a1 = __builtin_amdgcn_mfma_f32_16x16x32_bf16(af, wf1[ks], a1, 0, 0, 0);
      a2 = __builtin_amdgcn_mfma_f32_16x16x32_bf16(af, w2, a2, 0, 0, 0);
      a3 = __builtin_amdgcn_mfma_f32_16x16x32_bf16(af, w3, a3, 0, 0, 0);
    }
    const unsigned short* xv0 = (const unsigned short*)&xa0;  // gates i,f
    const unsigned short* xv1 = (const unsigned short*)&xa1;  // gates g,o
#pragma unroll
    for (int r = 0; r < 4; ++r) {
      float gi = a0[r] + bf2f(xv0[r]);
      float gf = a1[r] + bf2f(xv0[4 + r]);
      float gg = a2[r] + bf2f(xv1[r]);
      float go = a3[r] + bf2f(xv1[4 + r]);
      gi = sigmoid_f(gi);
      gf = sigmoid_f(gf);
      gg = tanh_f(gg);
      go = sigmoid_f(go);
      float c = gf * creg[r] + gi * gg;
      creg[r] = c;
      float h = go * tanh_f(c);
      hv[r] = h;
      *(unsigned short*)(hsw + r * (PH * 2)) = f2bf(h);
    }
    // prefetch next step's xg (global; no LDS hazard crossing the barrier)
    pxg += (size_t)16 * 1024 * 16;
    if (s + 1 < Ci) {
      xa0 = *(const uint4*)pxg;
      xa1 = *(const uint4*)(pxg + 8);
    }
    __syncthreads();
  }

  // persist state; final output on last chunk
#pragma unroll
  for (int r = 0; r < 4; ++r) {
    const size_t gidx = (size_t)(b0 + quad * 4 + r) * H_SZ + jcol;
    h_st[gidx] = f2bf(hv[r]);
    c_st[gidx] = creg[r];
  }
  if (t0 + Ci == T_STEPS) {
#pragma unroll
    for (int r = 0; r < 4; ++r) {
      const size_t gidx = (size_t)(b0 + quad * 4 + r) * H_SZ + jcol;
      out[gidx] = hv[r];
      out[(size_t)B_SZ * H_SZ + gidx] = creg[r];
    }
  }
}

extern "C" void kernel_launch(void* const* d_in, const int* in_sizes, int n_in,
                              void* d_out, int out_size, void* d_ws, size_t ws_size,
                              hipStream_t stream) {
  const int* enc = (const int*)d_in[0];
  const float* h0 = (const float*)d_in[1];
  const float* c0 = (const float*)d_in[2];
  const float* embed = (const float*)d_in[3];
  const float* W_ih = (const float*)d_in[4];
  const float* W_hh = (const float*)d_in[5];
  const float* b_ih = (const float*)d_in[6];
  const float* b_hh = (const float*)d_in[7];
  float* out = (float*)d_out;

  char* ws = (char*)d_ws;
  unsigned short* Wih_bf = (unsigned short*)(ws);                  // 512 KB
  unsigned short* Whh_bf = (unsigned short*)(ws + (512 << 10));    // 512 KB
  float* bias = (float*)(ws + (1024 << 10));                       // 4 KB
  unsigned short* h_st = (unsigned short*)(ws + (1028 << 10));     // 128 KB
  float* c_st = (float*)(ws + (1156 << 10));                       // 256 KB
  const size_t fixed = (size_t)(1412) << 10;
  unsigned short* xg = (unsigned short*)(ws + fixed);

  const size_t per_step = (size_t)B_SZ * G4H * 2;  // 512 KB per timestep (bf16)
  int C = 1;
  if (ws_size > fixed + per_step) {
    size_t c = (ws_size - fixed) / per_step;
    C = (c > T_STEPS) ? T_STEPS : (int)c;
  }

  prep_kernel<<<dim3(256), dim3(256), 0, stream>>>(h0, c0, W_ih, W_hh, b_ih, b_hh,
                                                   Wih_bf, Whh_bf, bias, h_st, c_st);
  for (int t0 = 0; t0 < T_STEPS; t0 += C) {
    int Ci = (T_STEPS - t0 < C) ? (T_STEPS - t0) : C;
    xgate_kernel<<<dim3(Ci * 4, 4), dim3(256), 0, stream>>>(enc, embed, Wih_bf, bias,
                                                            xg, t0, Ci);
    lstm_kernel<<<dim3(16), dim3(1024), 0, stream>>>(Whh_bf, xg, h_st, c_st,
                                                     out, t0, Ci);
  }
}